// Round 7
// baseline (5538.562 us; speedup 1.0000x reference)
//
#include <hip/hip_runtime.h>
#include <cstdint>
#include <cstddef>

// ---------------------------------------------------------------------------
// VWFutureModel: 2-layer GRU scan (T=128, N=256, C=64, U=512) + dense head.
// R7: XCD-local exchange (re-land of R6 idea, minus the risky custom barrier).
//  - WGs read HW_REG_XCC_ID and self-register; iff every XCD has exactly 32
//    WGs, fast mode: group m = physical XCD, slice n = registration slot.
//    ALL steady-state exchange is sc0-only (lines stay in the local L2);
//    weights stream from L3 (sequential, efficient path).
//  - Barriers in BOTH modes: the R4/R5-PROVEN device-scope gbarN (hip
//    atomics). No hand-rolled L2 barrier (R6's suspected hang source).
//  - Any registration anomaly -> R5-proven slow path (sc0 sc1 everywhere).
//    Both modes bit-identical; placement affects speed only. [G16-safe]
//  - Spin caps tightened: worst-case total barrier-failure cost ~10 s/exec.
// ---------------------------------------------------------------------------

#define NWG 256
#define TPB 512

constexpr int N_ = 256, T_ = 128, C_ = 64, U_ = 512, H_ = 256;

typedef __attribute__((ext_vector_type(8))) short short8;
typedef __attribute__((ext_vector_type(4))) float f32x4;
typedef __attribute__((ext_vector_type(4))) unsigned int u32x4;
typedef __attribute__((ext_vector_type(2))) unsigned int u32x2;

// ---------------- byte offsets in workspace (MFMA kernel) ------------------
constexpr size_t HPB      = 262144;                 // one h plane: 256*512*2B
constexpr size_t OFF_BAR  = 0;                      // 16384 B barrier+reg area
constexpr size_t OFF_HP   = 16384;                  // 2 bufs x [h1hi,h1lo,h2hi,h2lo]
constexpr size_t OFF_RH1  = OFF_HP + 8 * HPB;
constexpr size_t OFF_RH2  = OFF_RH1 + 524288;
constexpr size_t OFF_G1U  = OFF_RH2 + 524288;       // fp32 [256][512]
constexpr size_t OFF_G2U  = OFF_G1U + 524288;
constexpr size_t OFF_HID  = OFF_G2U + 524288;       // hid hi,lo (2*131072)
constexpr size_t OFF_XHI  = OFF_HID + 262144;       // [256][8192] bf16
constexpr size_t OFF_XLO  = OFF_XHI + 4194304;
constexpr size_t OFF_WG1S = OFF_XLO + 4194304;      // 32 * 81920
constexpr size_t OFF_WC1S = OFF_WG1S + 32 * 81920;  // 32 * 40960
constexpr size_t OFF_WG2S = OFF_WC1S + 32 * 40960;  // 32 * 131072
constexpr size_t OFF_WC2S = OFF_WG2S + 32 * 131072; // 32 * 65536
constexpr size_t OFF_WHS  = OFF_WC2S + 32 * 65536;  // 16 * 32768
constexpr size_t OFF_WPS  = OFF_WHS + 16 * 32768;   // 4 * 16384
constexpr size_t WS_NEED  = OFF_WPS + 4 * 16384;    // ~22.6 MiB

// barrier word layout (unsigned* barw):
//   group m (both modes): count @ 1024+m*32, epoch @ 1024+m*32+16
//   grid barrier: count @ 2048, epoch @ 2048+16
//   regcnt[16]:   @ 2112

// ---------------- scalar helpers -------------------------------------------
__device__ __forceinline__ float sigmoidf_(float z) {
  return 1.0f / (1.0f + __expf(-z));
}
__device__ __forceinline__ float tanhf_(float z) {
  return 1.0f - 2.0f / (1.0f + __expf(2.0f * z));
}
__device__ __forceinline__ unsigned short bf_hi(float f) {
  unsigned int x = __float_as_uint(f);
  unsigned int r = x + 0x7FFFu + ((x >> 16) & 1u);
  return (unsigned short)(r >> 16);
}
__device__ __forceinline__ float bf_f(unsigned v) {  // low 16 bits as bf16
  return __uint_as_float((v & 0xFFFFu) << 16);
}
__device__ __forceinline__ float bf_fh(unsigned v) {  // high 16 bits as bf16
  return __uint_as_float(v & 0xFFFF0000u);
}
__device__ __forceinline__ unsigned short bf_lo(float f, unsigned short hi) {
  return bf_hi(f - __uint_as_float(((unsigned)hi) << 16));
}

// ------------- coherent access, CH=1: XCD-local (sc0), CH=2: device --------
template <int CH>
__device__ __forceinline__ u32x4 ld128(const void* p) {
  u32x4 r;
  if constexpr (CH == 1)
    asm volatile("global_load_dwordx4 %0, %1, off sc0" : "=&v"(r) : "v"(p));
  else
    asm volatile("global_load_dwordx4 %0, %1, off sc0 sc1" : "=&v"(r) : "v"(p));
  return r;
}
template <int CH>
__device__ __forceinline__ void ldc2_b32(const void* p0, const void* p1,
                                         unsigned& a, unsigned& b) {
  if constexpr (CH == 1)
    asm volatile("global_load_dword %0, %2, off sc0\n\t"
                 "global_load_dword %1, %3, off sc0\n\t"
                 "s_waitcnt vmcnt(0)"
                 : "=&v"(a), "=&v"(b) : "v"(p0), "v"(p1));
  else
    asm volatile("global_load_dword %0, %2, off sc0 sc1\n\t"
                 "global_load_dword %1, %3, off sc0 sc1\n\t"
                 "s_waitcnt vmcnt(0)"
                 : "=&v"(a), "=&v"(b) : "v"(p0), "v"(p1));
}
template <int CH>
__device__ __forceinline__ void ldc3(const void* pq, const void* p0, const void* p1,
                                     u32x2& q, unsigned& a, unsigned& b) {
  if constexpr (CH == 1)
    asm volatile("global_load_dwordx2 %0, %3, off sc0\n\t"
                 "global_load_dword %1, %4, off sc0\n\t"
                 "global_load_dword %2, %5, off sc0\n\t"
                 "s_waitcnt vmcnt(0)"
                 : "=&v"(q), "=&v"(a), "=&v"(b) : "v"(pq), "v"(p0), "v"(p1));
  else
    asm volatile("global_load_dwordx2 %0, %3, off sc0 sc1\n\t"
                 "global_load_dword %1, %4, off sc0 sc1\n\t"
                 "global_load_dword %2, %5, off sc0 sc1\n\t"
                 "s_waitcnt vmcnt(0)"
                 : "=&v"(q), "=&v"(a), "=&v"(b) : "v"(pq), "v"(p0), "v"(p1));
}
template <int CH>
__device__ __forceinline__ void stc_b32(void* p, unsigned v) {
  if constexpr (CH == 1)
    asm volatile("global_store_dword %0, %1, off sc0" :: "v"(p), "v"(v) : "memory");
  else
    asm volatile("global_store_dword %0, %1, off sc0 sc1" :: "v"(p), "v"(v) : "memory");
}
template <int CH>
__device__ __forceinline__ void stc_b64(void* p, u32x2 v) {
  if constexpr (CH == 1)
    asm volatile("global_store_dwordx2 %0, %1, off sc0" :: "v"(p), "v"(v) : "memory");
  else
    asm volatile("global_store_dwordx2 %0, %1, off sc0 sc1" :: "v"(p), "v"(v) : "memory");
}

// ---------------- barriers (PROVEN primitives only) ------------------------
// Device-scope group barrier (R4/R5-proven). vmcnt(0) drain first so all
// sc0/sc0sc1 stores have reached their coherence point (local L2 suffices
// for XCD-local consumers; L3 for device consumers).
__device__ __forceinline__ void gbarN(unsigned* b, unsigned np) {
  asm volatile("s_waitcnt vmcnt(0) lgkmcnt(0)" ::: "memory");
  __syncthreads();
  if (threadIdx.x == 0) {
    unsigned e = __hip_atomic_load(b + 16, __ATOMIC_RELAXED, __HIP_MEMORY_SCOPE_AGENT);
    unsigned a = __hip_atomic_fetch_add(b, 1u, __ATOMIC_RELAXED, __HIP_MEMORY_SCOPE_AGENT);
    if (a == np - 1) {
      __hip_atomic_store(b, 0u, __ATOMIC_RELAXED, __HIP_MEMORY_SCOPE_AGENT);
      __hip_atomic_store(b + 16, e + 1u, __ATOMIC_RELAXED, __HIP_MEMORY_SCOPE_AGENT);
    } else {
      unsigned spins = 0;
      while (__hip_atomic_load(b + 16, __ATOMIC_RELAXED, __HIP_MEMORY_SCOPE_AGENT) == e) {
        __builtin_amdgcn_s_sleep(1);
        if (++spins > (1u << 17)) break;  // bounded: fail fast, never hang
      }
    }
  }
  __syncthreads();
}

// Fully-fenced barrier (prologue + fallback kernel).
__device__ __forceinline__ void gbarF(unsigned* b, unsigned np) {
  __syncthreads();
  if (threadIdx.x == 0) {
    __threadfence();
    unsigned e = __hip_atomic_load(b + 16, __ATOMIC_RELAXED, __HIP_MEMORY_SCOPE_AGENT);
    unsigned a = __hip_atomic_fetch_add(b, 1u, __ATOMIC_ACQ_REL, __HIP_MEMORY_SCOPE_AGENT);
    if (a == np - 1) {
      __hip_atomic_store(b, 0u, __ATOMIC_RELAXED, __HIP_MEMORY_SCOPE_AGENT);
      __hip_atomic_store(b + 16, e + 1u, __ATOMIC_RELEASE, __HIP_MEMORY_SCOPE_AGENT);
    } else {
      unsigned spins = 0;
      while (__hip_atomic_load(b + 16, __ATOMIC_RELAXED, __HIP_MEMORY_SCOPE_AGENT) == e) {
        __builtin_amdgcn_s_sleep(1);
        if (++spins > (1u << 20)) break;
      }
    }
    __threadfence();
  }
  __syncthreads();
}

// ---------------- weight stream swizzle (prologue; zero-padded) ------------
__device__ void writeStream(const float* __restrict__ W, int ldW, int colbase,
                            char* sb, int nsplit, int slots, int tnn, int nch) {
  const int tid = threadIdx.x;
  const int lane = tid & 63;
  const int e = tid >> 6;  // 0..7
  const int nf = nsplit * slots * tnn;
  for (int f = 0; f < nf; ++f) {
    int tn = f % tnn;
    int ci = (f / tnn) % slots;
    int ks = f / (tnn * slots);
    int c = ks + ci * nsplit;
    int k = 32 * c + ((lane >> 4) << 3) + e;
    int col = colbase + 16 * tn + (lane & 15);
    float v = (c < nch) ? W[(size_t)k * ldW + col] : 0.f;
    unsigned short hi = bf_hi(v);
    unsigned short lo = bf_lo(v, hi);
    unsigned short* fb = (unsigned short*)(sb + (size_t)f * 2048);
    fb[lane * 8 + e] = hi;
    fb[512 + lane * 8 + e] = lo;
  }
}

// ---------------- MFMA core (no internal syncs) ----------------------------
template <int TM, int TN, int NSPLIT, int SLOTS, int KA, int CH>
__device__ __forceinline__ void mm_core(
    const unsigned short* __restrict__ A1h, const unsigned short* __restrict__ A1l,
    int lda1, int aoff,
    const unsigned short* __restrict__ A2h, const unsigned short* __restrict__ A2l,
    int lda2, const char* __restrict__ bstr, float* red, int row0loc) {
  const int tid = threadIdx.x;
  const int ww = tid >> 6, lane = tid & 63;
  const int tm = ww / NSPLIT;
  const int ks = ww % NSPLIT;
  const int arow = row0loc + 16 * tm + (lane & 15);
  const int kgrp = (lane >> 4) << 3;

  u32x4 Ah[SLOTS], Al[SLOTS];
#pragma unroll
  for (int ci = 0; ci < SLOTS; ++ci) {
    const int c = ks + ci * NSPLIT;
    const int ak = 32 * c + kgrp;
    const unsigned short *ph, *pl;
    if (ak < KA) {
      ph = A1h + (size_t)arow * lda1 + aoff + ak;
      pl = A1l + (size_t)arow * lda1 + aoff + ak;
    } else {
      const int ak2 = ak - KA;
      ph = A2h + (size_t)arow * lda2 + ak2;
      pl = A2l + (size_t)arow * lda2 + ak2;
    }
    Ah[ci] = ld128<CH>(ph);
    Al[ci] = ld128<CH>(pl);
  }
  asm volatile("s_waitcnt vmcnt(0)" ::: "memory");
  __builtin_amdgcn_sched_barrier(0);  // rule #18

  f32x4 acc0[TN], acc1[TN], acc2[TN];
#pragma unroll
  for (int tn = 0; tn < TN; ++tn) {
    acc0[tn] = (f32x4){0.f, 0.f, 0.f, 0.f};
    acc1[tn] = (f32x4){0.f, 0.f, 0.f, 0.f};
    acc2[tn] = (f32x4){0.f, 0.f, 0.f, 0.f};
  }
#pragma unroll
  for (int ci = 0; ci < SLOTS; ++ci) {
    union { u32x4 u; short8 s; } ah, al;
    ah.u = Ah[ci]; al.u = Al[ci];
    const char* fb = bstr + ((size_t)(ks * SLOTS + ci) * TN) * 2048;
#pragma unroll
    for (int tn = 0; tn < TN; ++tn) {
      union { uint4 u; short8 s; } bh, bl;
      bh.u = *(const uint4*)((const unsigned short*)(fb + (size_t)tn * 2048) + lane * 8);
      bl.u = *(const uint4*)((const unsigned short*)(fb + (size_t)tn * 2048 + 1024) + lane * 8);
      acc0[tn] = __builtin_amdgcn_mfma_f32_16x16x32_bf16(ah.s, bh.s, acc0[tn], 0, 0, 0);
      acc1[tn] = __builtin_amdgcn_mfma_f32_16x16x32_bf16(ah.s, bl.s, acc1[tn], 0, 0, 0);
      acc2[tn] = __builtin_amdgcn_mfma_f32_16x16x32_bf16(al.s, bh.s, acc2[tn], 0, 0, 0);
    }
  }
#pragma unroll
  for (int tn = 0; tn < TN; ++tn) {
    f32x4 s = acc0[tn] + acc1[tn] + acc2[tn];
    int slot = (tm * TN + tn) * NSPLIT + ks;
    *(f32x4*)(&red[slot * 256 + lane * 4]) = s;
  }
}

// reduce partials + run epilogue per COLUMN-PAIR (col, col+1)
template <int TM, int TN, int NSPLIT, typename F>
__device__ __forceinline__ void epi2(const float* red, int row0loc, int col0, F f) {
  for (int idx = threadIdx.x; idx < TM * TN * 128; idx += TPB) {
    int tg = idx >> 7;
    int r  = (idx >> 3) & 15;
    int cp = idx & 7;
    int e0 = (((((r >> 2) << 4) | (cp << 1)) << 2) | (r & 3));
    float z0 = 0.f, z1 = 0.f;
#pragma unroll
    for (int s = 0; s < NSPLIT; ++s) {
      const float* rp = red + (tg * NSPLIT + s) * 256;
      z0 += rp[e0];
      z1 += rp[e0 + 4];
    }
    int tm = tg / TN, tn = tg % TN;
    f(row0loc + 16 * tm + r, col0 + 16 * tn + cp * 2, z0, z1);
  }
}

// ---------------- steady-state step loop -----------------------------------
// FAST: exchange data sc0-only (XCD-local L2); SLOW: sc0 sc1 (device).
// Barriers identical (device-scope gbarN) in both modes.
template <bool FAST>
__device__ void run_steps(char* __restrict__ wsb, float* __restrict__ out,
                          const float* __restrict__ bg1, const float* __restrict__ bc1,
                          const float* __restrict__ bg2, const float* __restrict__ bc2,
                          const float* __restrict__ bh, const float* __restrict__ bp,
                          int m, int n, unsigned* gb, float* red) {
  constexpr int CH = FAST ? 1 : 2;
  const int row0 = m * 32;

  unsigned short* xhi = (unsigned short*)(wsb + OFF_XHI);
  unsigned short* xlo = (unsigned short*)(wsb + OFF_XLO);
  unsigned short* rh1hi = (unsigned short*)(wsb + OFF_RH1);
  unsigned short* rh1lo = (unsigned short*)(wsb + OFF_RH1 + 262144);
  unsigned short* rh2hi = (unsigned short*)(wsb + OFF_RH2);
  unsigned short* rh2lo = (unsigned short*)(wsb + OFF_RH2 + 262144);
  float* g1u = (float*)(wsb + OFF_G1U);
  float* g2u = (float*)(wsb + OFF_G2U);
  unsigned short* hidhi = (unsigned short*)(wsb + OFF_HID);
  unsigned short* hidlo = (unsigned short*)(wsb + OFF_HID + 131072);

  const char* wg1s = (const char*)(wsb + OFF_WG1S + (size_t)n * 81920);
  const char* wc1s = (const char*)(wsb + OFF_WC1S + (size_t)n * 40960);
  const char* wg2s = (const char*)(wsb + OFF_WG2S + (size_t)n * 131072);
  const char* wc2s = (const char*)(wsb + OFF_WC2S + (size_t)n * 65536);
  const int b2 = n & 15, a2 = n >> 4;
  const int b4 = n & 3, a4 = (n >> 2) & 1;
  const char* whs = (const char*)(wsb + OFF_WHS + (size_t)b2 * 32768);
  const char* wps = (const char*)(wsb + OFF_WPS + (size_t)b4 * 16384);

  for (int t = 0; t <= T_; ++t) {
    const int p = t & 1, q = p ^ 1;
    unsigned short* h1hi_p = (unsigned short*)(wsb + OFF_HP + (size_t)p * 4 * HPB);
    unsigned short* h1lo_p = h1hi_p + 131072;
    unsigned short* h2hi_p = h1hi_p + 262144;
    unsigned short* h2lo_p = h1hi_p + 393216;
    unsigned short* h1hi_q = (unsigned short*)(wsb + OFF_HP + (size_t)q * 4 * HPB);
    unsigned short* h1lo_q = h1hi_q + 131072;

    // ================= slot A: P1 gates1 =================
    if (t < T_) {
      mm_core<2, 2, 4, 5, 64, CH>(xhi, xlo, 8192, t * 64, h1hi_p, h1lo_p, 512,
                                  wg1s, red, row0);
      __syncthreads();
      epi2<2, 2, 4>(red, row0, n * 32, [&](int row, int col, float z0, float z1) {
        z0 += bg1[col]; z1 += bg1[col + 1];
        float s0 = sigmoidf_(z0), s1 = sigmoidf_(z1);
        if (col < 512) {
          size_t ix = (size_t)row * 512 + col;
          unsigned hw, lw;
          ldc2_b32<CH>(h1hi_p + ix, h1lo_p + ix, hw, lw);
          float h0 = bf_f(hw) + bf_f(lw);
          float h1v = bf_fh(hw) + bf_fh(lw);
          float r0 = s0 * h0, r1 = s1 * h1v;
          unsigned short a0 = bf_hi(r0), a1 = bf_hi(r1);
          stc_b32<CH>(rh1hi + ix, (unsigned)a0 | ((unsigned)a1 << 16));
          stc_b32<CH>(rh1lo + ix, (unsigned)bf_lo(r0, a0) | ((unsigned)bf_lo(r1, a1) << 16));
        } else {
          u32x2 g = {__float_as_uint(s0), __float_as_uint(s1)};
          stc_b64<CH>(g1u + (size_t)row * 512 + (col - 512), g);
        }
      });
    }
    gbarN(gb, 32);

    // ================= slot B: P2 cand1 | P2b head-dense =================
    if (t < T_)
      mm_core<2, 1, 4, 5, 64, CH>(xhi, xlo, 8192, t * 64, rh1hi, rh1lo, 512,
                                  wc1s, red, row0);
    if (t > 0)
      mm_core<1, 1, 8, 2, 512, CH>(h2hi_p, h2lo_p, 512, 0, nullptr, nullptr, 0,
                                   whs, red + 2048, row0 + 16 * a2);
    __syncthreads();
    if (t < T_) {
      epi2<2, 1, 4>(red, row0, n * 16, [&](int row, int col, float z0, float z1) {
        z0 += bc1[col]; z1 += bc1[col + 1];
        float c0 = tanhf_(z0), c1 = tanhf_(z1);
        size_t ix = (size_t)row * 512 + col;
        u32x2 ug; unsigned hw, lw;
        ldc3<CH>(g1u + ix, h1hi_p + ix, h1lo_p + ix, ug, hw, lw);
        float u0 = __uint_as_float(ug.x), u1 = __uint_as_float(ug.y);
        float h0 = bf_f(hw) + bf_f(lw);
        float h1v = bf_fh(hw) + bf_fh(lw);
        float n0 = u0 * h0 + (1.f - u0) * c0;
        float n1 = u1 * h1v + (1.f - u1) * c1;
        unsigned short a0 = bf_hi(n0), a1 = bf_hi(n1);
        stc_b32<CH>(h1hi_q + ix, (unsigned)a0 | ((unsigned)a1 << 16));
        stc_b32<CH>(h1lo_q + ix, (unsigned)bf_lo(n0, a0) | ((unsigned)bf_lo(n1, a1) << 16));
      });
    }
    if (t > 0) {
      epi2<1, 1, 8>(red + 2048, row0 + 16 * a2, 16 * b2,
                    [&](int row, int col, float z0, float z1) {
        z0 += bh[col]; z1 += bh[col + 1];
        float e0v = z0 > 0.f ? z0 : __expf(z0) - 1.f;
        float e1v = z1 > 0.f ? z1 : __expf(z1) - 1.f;
        size_t ix = (size_t)row * 256 + col;
        unsigned short a0 = bf_hi(e0v), a1 = bf_hi(e1v);
        stc_b32<CH>(hidhi + ix, (unsigned)a0 | ((unsigned)a1 << 16));
        stc_b32<CH>(hidlo + ix, (unsigned)bf_lo(e0v, a0) | ((unsigned)bf_lo(e1v, a1) << 16));
      });
    }
    gbarN(gb, 32);

    // ================= slot C: P3 gates2 =================
    if (t < T_) {
      mm_core<2, 2, 4, 8, 512, CH>(h1hi_q, h1lo_q, 512, 0, h2hi_p, h2lo_p, 512,
                                   wg2s, red, row0);
      __syncthreads();
      epi2<2, 2, 4>(red, row0, n * 32, [&](int row, int col, float z0, float z1) {
        z0 += bg2[col]; z1 += bg2[col + 1];
        float s0 = sigmoidf_(z0), s1 = sigmoidf_(z1);
        if (col < 512) {
          size_t ix = (size_t)row * 512 + col;
          unsigned hw, lw;
          ldc2_b32<CH>(h2hi_p + ix, h2lo_p + ix, hw, lw);
          float h0 = bf_f(hw) + bf_f(lw);
          float h1v = bf_fh(hw) + bf_fh(lw);
          float r0 = s0 * h0, r1 = s1 * h1v;
          unsigned short a0 = bf_hi(r0), a1 = bf_hi(r1);
          stc_b32<CH>(rh2hi + ix, (unsigned)a0 | ((unsigned)a1 << 16));
          stc_b32<CH>(rh2lo + ix, (unsigned)bf_lo(r0, a0) | ((unsigned)bf_lo(r1, a1) << 16));
        } else {
          u32x2 g = {__float_as_uint(s0), __float_as_uint(s1)};
          stc_b64<CH>(g2u + (size_t)row * 512 + (col - 512), g);
        }
      });
    }
    gbarN(gb, 32);

    // ================= slot D: P4 cand2 | P4b out-proj =================
    {
      unsigned short* h2hi_q = h1hi_q + 262144;
      unsigned short* h2lo_q = h1hi_q + 393216;
      if (t < T_)
        mm_core<2, 1, 4, 8, 512, CH>(h1hi_q, h1lo_q, 512, 0, rh2hi, rh2lo, 512,
                                     wc2s, red, row0);
      if (t > 0 && n < 8)
        mm_core<1, 1, 8, 1, 256, CH>(hidhi, hidlo, 256, 0, nullptr, nullptr, 0,
                                     wps, red + 2048, row0 + 16 * a4);
      __syncthreads();
      if (t < T_) {
        epi2<2, 1, 4>(red, row0, n * 16, [&](int row, int col, float z0, float z1) {
          z0 += bc2[col]; z1 += bc2[col + 1];
          float c0 = tanhf_(z0), c1 = tanhf_(z1);
          size_t ix = (size_t)row * 512 + col;
          u32x2 ug; unsigned hw, lw;
          ldc3<CH>(g2u + ix, h2hi_p + ix, h2lo_p + ix, ug, hw, lw);
          float u0 = __uint_as_float(ug.x), u1 = __uint_as_float(ug.y);
          float h0 = bf_f(hw) + bf_f(lw);
          float h1v = bf_fh(hw) + bf_fh(lw);
          float n0 = u0 * h0 + (1.f - u0) * c0;
          float n1 = u1 * h1v + (1.f - u1) * c1;
          unsigned short a0 = bf_hi(n0), a1 = bf_hi(n1);
          stc_b32<CH>(h2hi_q + ix, (unsigned)a0 | ((unsigned)a1 << 16));
          stc_b32<CH>(h2lo_q + ix, (unsigned)bf_lo(n0, a0) | ((unsigned)bf_lo(n1, a1) << 16));
        });
      }
      if (t > 0 && n < 8) {
        epi2<1, 1, 8>(red + 2048, row0 + 16 * a4, 16 * b4,
                      [&](int row, int col, float z0, float z1) {
          float2 v = {z0 + bp[col], z1 + bp[col + 1]};
          *(float2*)(out + (size_t)row * 8192 + (size_t)(t - 1) * 64 + col) = v;
        });
      }
    }
    __syncthreads();  // protect red before next step's slot A rewrite
  }
}

// ---------------- MFMA kernel ----------------------------------------------
extern "C" __global__ __launch_bounds__(TPB, 2)
void gru_mfma(const float* __restrict__ frames,
              const float* __restrict__ Wg1, const float* __restrict__ bg1,
              const float* __restrict__ Wc1, const float* __restrict__ bc1,
              const float* __restrict__ Wg2, const float* __restrict__ bg2,
              const float* __restrict__ Wc2, const float* __restrict__ bc2,
              const float* __restrict__ Wh,  const float* __restrict__ bh,
              const float* __restrict__ Wp,  const float* __restrict__ bp,
              float* __restrict__ out, char* __restrict__ wsb) {
  __shared__ float red[4096];  // 16 KB
  __shared__ unsigned sh_dyn[2];

  const int tid = threadIdx.x;
  const int wg = blockIdx.x;

  unsigned* barw = (unsigned*)(wsb + OFF_BAR);
  unsigned* allb = barw + 2048;
  unsigned* regcnt = barw + 2112;

  unsigned short* xhi = (unsigned short*)(wsb + OFF_XHI);
  unsigned short* xlo = (unsigned short*)(wsb + OFF_XLO);

  // ---- registration: physical XCD id + slot (placement-verified) ----
  {
    unsigned xcc;
    asm volatile("s_getreg_b32 %0, hwreg(20, 0, 32)" : "=s"(xcc));
    xcc &= 15u;
    if (tid == 0) {
      unsigned slot = __hip_atomic_fetch_add(regcnt + xcc, 1u, __ATOMIC_RELAXED,
                                             __HIP_MEMORY_SCOPE_AGENT);
      sh_dyn[0] = xcc;
      sh_dyn[1] = slot;
    }
  }

  // ---- prologue: x planes ----
  {
    const size_t base = (size_t)wg * 8192;
    for (int i = tid; i < 8192; i += TPB) {
      float v = frames[base + i];
      unsigned short h = bf_hi(v);
      xhi[base + i] = h;
      xlo[base + i] = bf_lo(v, h);
    }
  }
  // ---- prologue: weight streams (static wg assignment) ----
  {
    const int sxcd = wg & 7;
    const int sgrp = wg >> 3;
    const int sm = sgrp >> 2;
    const int sn = (sxcd << 2) | (sgrp & 3);
    if (sm == 0) {
      writeStream(Wg1, 1024, sn * 32, wsb + OFF_WG1S + (size_t)sn * 81920, 4, 5, 2, 18);
      writeStream(Wc1, 512, sn * 16, wsb + OFF_WC1S + (size_t)sn * 40960, 4, 5, 1, 18);
      writeStream(Wg2, 1024, sn * 32, wsb + OFF_WG2S + (size_t)sn * 131072, 4, 8, 2, 32);
      writeStream(Wc2, 512, sn * 16, wsb + OFF_WC2S + (size_t)sn * 65536, 4, 8, 1, 32);
    }
    if (wg < 16) writeStream(Wh, 256, wg * 16, wsb + OFF_WHS + (size_t)wg * 32768, 8, 2, 1, 16);
    if (wg < 4)  writeStream(Wp, 64, wg * 16, wsb + OFF_WPS + (size_t)wg * 16384, 8, 1, 1, 8);
  }
  gbarF(allb, NWG);  // fenced: publish x + weights + registrations, once

  // ---- mode resolution: fast iff every XCD has exactly 32 WGs ----
  bool fast = true;
  for (int x = 0; x < 16; ++x) {
    unsigned c = __hip_atomic_load(regcnt + x, __ATOMIC_RELAXED, __HIP_MEMORY_SCOPE_AGENT);
    fast = fast && (c == ((x < 8) ? 32u : 0u));
  }

  if (fast) {
    const int fm = (int)sh_dyn[0];
    const int fn = (int)sh_dyn[1];
    run_steps<true>(wsb, out, bg1, bc1, bg2, bc2, bh, bp, fm, fn,
                    barw + 1024 + fm * 32, red);
  } else {
    const int sxcd = wg & 7;
    const int sgrp = wg >> 3;
    const int sm = sgrp >> 2;
    const int sn = (sxcd << 2) | (sgrp & 3);
    run_steps<false>(wsb, out, bg1, bc1, bg2, bc2, bh, bp, sm, sn,
                     barw + 1024 + sm * 32, red);
  }
}

// ======================= R2 fallback (proven fp32 path) ====================
constexpr size_t F_SZ_H   = (size_t)N_ * U_;
constexpr size_t F_OFF_H1 = 0;
constexpr size_t F_OFF_H2 = F_OFF_H1 + 2 * F_SZ_H;
constexpr size_t F_OFF_BAR = F_OFF_H2 + 2 * F_SZ_H;
constexpr size_t F_OFF_G1 = F_OFF_BAR + 64;
constexpr size_t F_OFF_G2 = F_OFF_G1 + (size_t)N_ * 1024;
constexpr size_t F_OFF_HID = F_OFF_G2 + (size_t)N_ * 1024;
constexpr int LDP = 257;

template <int CK, bool GATED>
__device__ __forceinline__ void stage(float (*lds)[LDP],
                                      const float* __restrict__ src, int sStride, int sOff,
                                      const float* __restrict__ gate, int gStride, int gOff,
                                      int row0) {
  constexpr int PER = CK / 16;
  const int r = threadIdx.x >> 4;
  const int c0 = (threadIdx.x & 15) * PER;
  const float* s = src + (size_t)(row0 + r) * sStride + sOff + c0;
  float4 a0, a1, a2, a3;
  a0 = *(const float4*)(s);
  if constexpr (PER >= 8) a1 = *(const float4*)(s + 4);
  if constexpr (PER >= 16) { a2 = *(const float4*)(s + 8); a3 = *(const float4*)(s + 12); }
  if constexpr (GATED) {
    const float* g = gate + (size_t)(row0 + r) * gStride + gOff + c0;
    float4 g0 = *(const float4*)(g);
    a0.x *= g0.x; a0.y *= g0.y; a0.z *= g0.z; a0.w *= g0.w;
    if constexpr (PER >= 8) {
      float4 g1v = *(const float4*)(g + 4);
      a1.x *= g1v.x; a1.y *= g1v.y; a1.z *= g1v.z; a1.w *= g1v.w;
    }
    if constexpr (PER >= 16) {
      float4 g2v = *(const float4*)(g + 8);
      float4 g3v = *(const float4*)(g + 12);
      a2.x *= g2v.x; a2.y *= g2v.y; a2.z *= g2v.z; a2.w *= g2v.w;
      a3.x *= g3v.x; a3.y *= g3v.y; a3.z *= g3v.z; a3.w *= g3v.w;
    }
  }
  float* d = &lds[r][c0];
  d[0] = a0.x; d[1] = a0.y; d[2] = a0.z; d[3] = a0.w;
  if constexpr (PER >= 8) { d[4] = a1.x; d[5] = a1.y; d[6] = a1.z; d[7] = a1.w; }
  if constexpr (PER >= 16) {
    d[8] = a2.x; d[9] = a2.y; d[10] = a2.z; d[11] = a2.w;
    d[12] = a3.x; d[13] = a3.y; d[14] = a3.z; d[15] = a3.w;
  }
}
template <int CK>
__device__ __forceinline__ void fma2(float2& acc, const float (*lds)[LDP], int row,
                                     const float* __restrict__ B, int ldB) {
#pragma unroll 8
  for (int k = 0; k < CK; ++k) {
    const float a = lds[row][k];
    const float2 b = *(const float2*)(B + (size_t)k * ldB);
    acc.x = fmaf(a, b.x, acc.x);
    acc.y = fmaf(a, b.y, acc.y);
  }
}
template <int CK>
__device__ __forceinline__ void fma1(float& acc, const float (*lds)[LDP], int row,
                                     const float* __restrict__ B, int ldB) {
#pragma unroll 8
  for (int k = 0; k < CK; ++k) acc = fmaf(lds[row][k], B[(size_t)k * ldB], acc);
}

extern "C" __global__ __launch_bounds__(TPB, 2)
void gru_persistent(const float* __restrict__ frames,
                    const float* __restrict__ Wg1, const float* __restrict__ bg1,
                    const float* __restrict__ Wc1, const float* __restrict__ bc1,
                    const float* __restrict__ Wg2, const float* __restrict__ bg2,
                    const float* __restrict__ Wc2, const float* __restrict__ bc2,
                    const float* __restrict__ Wh,  const float* __restrict__ bh,
                    const float* __restrict__ Wp,  const float* __restrict__ bp,
                    float* __restrict__ out, float* __restrict__ ws) {
  __shared__ float lds[32][LDP];
  float* h1b = ws + F_OFF_H1;
  float* h2b = ws + F_OFF_H2;
  unsigned* bar = (unsigned*)(ws + F_OFF_BAR);
  float* g1 = ws + F_OFF_G1;
  float* g2 = ws + F_OFF_G2;
  float* hid = ws + F_OFF_HID;
  const int tid = threadIdx.x;
  const int wg = blockIdx.x;
  const int xcd = wg & 7, grp = wg >> 3;
  const int m_blk = grp >> 2, n_blk = (xcd << 2) | (grp & 3);
  const int row0 = m_blk * 32;
  const int rowA = tid & 31, cq = tid >> 5;
  const int nrow = row0 + rowA;
  for (int t = 0; t <= T_; ++t) {
    const int p = t & 1;
    const float* h1o = h1b + (size_t)p * F_SZ_H;
    float* h1n = h1b + (size_t)(p ^ 1) * F_SZ_H;
    const float* h2o = h2b + (size_t)p * F_SZ_H;
    float* h2n = h2b + (size_t)(p ^ 1) * F_SZ_H;
    if (t < T_) {
      float2 acc = {0.f, 0.f};
      const int col = n_blk * 32 + cq * 2;
      stage<64, false>(lds, frames, T_ * C_, t * C_, nullptr, 0, 0, row0);
      __syncthreads();
      fma2<64>(acc, lds, rowA, Wg1 + col, 1024);
      __syncthreads();
#pragma unroll 1
      for (int ch = 0; ch < 2; ++ch) {
        stage<256, false>(lds, h1o, U_, ch * 256, nullptr, 0, 0, row0);
        __syncthreads();
        fma2<256>(acc, lds, rowA, Wg1 + (size_t)(64 + ch * 256) * 1024 + col, 1024);
        __syncthreads();
      }
      const float2 bb = *(const float2*)(bg1 + col);
      float* gp = g1 + (size_t)nrow * 1024 + col;
      gp[0] = sigmoidf_(acc.x + bb.x);
      gp[1] = sigmoidf_(acc.y + bb.y);
    }
    gbarF(bar, NWG);
    if (t < T_) {
      float acc = 0.f;
      const int col = n_blk * 16 + cq;
      stage<64, false>(lds, frames, T_ * C_, t * C_, nullptr, 0, 0, row0);
      __syncthreads();
      fma1<64>(acc, lds, rowA, Wc1 + col, U_);
      __syncthreads();
#pragma unroll 1
      for (int ch = 0; ch < 2; ++ch) {
        stage<256, true>(lds, h1o, U_, ch * 256, g1, 1024, ch * 256, row0);
        __syncthreads();
        fma1<256>(acc, lds, rowA, Wc1 + (size_t)(64 + ch * 256) * U_ + col, U_);
        __syncthreads();
      }
      const float cv = tanhf_(acc + bc1[col]);
      const float u = g1[(size_t)nrow * 1024 + 512 + col];
      const float ho = h1o[(size_t)nrow * U_ + col];
      h1n[(size_t)nrow * U_ + col] = u * ho + (1.f - u) * cv;
    }
    if (t > 0) {
      float acc = 0.f;
      const int col = n_blk * 8 + (cq & 7);
      const bool act = tid < 256;
#pragma unroll 1
      for (int ch = 0; ch < 2; ++ch) {
        stage<256, false>(lds, h2o, U_, ch * 256, nullptr, 0, 0, row0);
        __syncthreads();
        if (act) fma1<256>(acc, lds, rowA, Wh + (size_t)(ch * 256) * H_ + col, H_);
        __syncthreads();
      }
      if (act) {
        const float z = acc + bh[col];
        hid[(size_t)nrow * H_ + col] = z > 0.f ? z : __expf(z) - 1.f;
      }
    }
    gbarF(bar, NWG);
    if (t < T_) {
      float2 acc = {0.f, 0.f};
      const int col = n_blk * 32 + cq * 2;
#pragma unroll 1
      for (int ch = 0; ch < 4; ++ch) {
        const float* src = (ch < 2) ? h1n : h2o;
        stage<256, false>(lds, src, U_, (ch & 1) * 256, nullptr, 0, 0, row0);
        __syncthreads();
        fma2<256>(acc, lds, rowA, Wg2 + (size_t)(ch * 256) * 1024 + col, 1024);
        __syncthreads();
      }
      const float2 bb = *(const float2*)(bg2 + col);
      float* gp = g2 + (size_t)nrow * 1024 + col;
      gp[0] = sigmoidf_(acc.x + bb.x);
      gp[1] = sigmoidf_(acc.y + bb.y);
    }
    gbarF(bar, NWG);
    if (t < T_) {
      float acc = 0.f;
      const int col = n_blk * 16 + cq;
#pragma unroll 1
      for (int ch = 0; ch < 4; ++ch) {
        if (ch < 2) stage<256, false>(lds, h1n, U_, (ch & 1) * 256, nullptr, 0, 0, row0);
        else stage<256, true>(lds, h2o, U_, (ch & 1) * 256, g2, 1024, (ch & 1) * 256, row0);
        __syncthreads();
        fma1<256>(acc, lds, rowA, Wc2 + (size_t)(ch * 256) * U_ + col, U_);
        __syncthreads();
      }
      const float cv = tanhf_(acc + bc2[col]);
      const float u = g2[(size_t)nrow * 1024 + 512 + col];
      const float ho = h2o[(size_t)nrow * U_ + col];
      h2n[(size_t)nrow * U_ + col] = u * ho + (1.f - u) * cv;
    }
    if (t > 0) {
      if (tid < 64) {
        float acc = 0.f;
        const int col = n_blk * 2 + cq;
        const float* hrow = hid + (size_t)nrow * H_;
#pragma unroll 8
        for (int k = 0; k < H_; ++k) acc = fmaf(hrow[k], Wp[(size_t)k * C_ + col], acc);
        out[(size_t)nrow * (T_ * C_) + (size_t)(t - 1) * C_ + col] = acc + bp[col];
      }
    }
  }
}

// ---------------- launch ---------------------------------------------------
extern "C" void kernel_launch(void* const* d_in, const int* in_sizes, int n_in,
                              void* d_out, int out_size, void* d_ws, size_t ws_size,
                              hipStream_t stream) {
  const float* frames = (const float*)d_in[0];
  const float* Wg1 = (const float*)d_in[1];
  const float* bg1 = (const float*)d_in[2];
  const float* Wc1 = (const float*)d_in[3];
  const float* bc1 = (const float*)d_in[4];
  const float* Wg2 = (const float*)d_in[5];
  const float* bg2 = (const float*)d_in[6];
  const float* Wc2 = (const float*)d_in[7];
  const float* bc2 = (const float*)d_in[8];
  const float* Wh = (const float*)d_in[9];
  const float* bh = (const float*)d_in[10];
  const float* Wp = (const float*)d_in[11];
  const float* bp = (const float*)d_in[12];
  float* out = (float*)d_out;

  if (ws_size >= WS_NEED) {
    char* wsb = (char*)d_ws;
    // zero barrier+registration area + h-plane buffer 0
    hipMemsetAsync(d_ws, 0, 16384 + 4 * HPB, stream);
    void* args[] = {(void*)&frames, (void*)&Wg1, (void*)&bg1, (void*)&Wc1, (void*)&bc1,
                    (void*)&Wg2, (void*)&bg2, (void*)&Wc2, (void*)&bc2,
                    (void*)&Wh, (void*)&bh, (void*)&Wp, (void*)&bp,
                    (void*)&out, (void*)&wsb};
    hipError_t err = hipLaunchCooperativeKernel((const void*)gru_mfma,
                                                dim3(NWG), dim3(TPB), args, 0, stream);
    if (err != hipSuccess) {
      (void)hipGetLastError();
      hipLaunchKernelGGL(gru_mfma, dim3(NWG), dim3(TPB), 0, stream,
                         frames, Wg1, bg1, Wc1, bc1, Wg2, bg2, Wc2, bc2,
                         Wh, bh, Wp, bp, out, wsb);
    }
  } else {
    float* ws = (float*)d_ws;
    hipMemsetAsync(d_ws, 0, F_OFF_G1 * sizeof(float), stream);
    void* args[] = {(void*)&frames, (void*)&Wg1, (void*)&bg1, (void*)&Wc1, (void*)&bc1,
                    (void*)&Wg2, (void*)&bg2, (void*)&Wc2, (void*)&bc2,
                    (void*)&Wh, (void*)&bh, (void*)&Wp, (void*)&bp,
                    (void*)&out, (void*)&ws};
    hipError_t err = hipLaunchCooperativeKernel((const void*)gru_persistent,
                                                dim3(NWG), dim3(TPB), args, 0, stream);
    if (err != hipSuccess) {
      (void)hipGetLastError();
      hipLaunchKernelGGL(gru_persistent, dim3(NWG), dim3(TPB), 0, stream,
                         frames, Wg1, bg1, Wc1, bc1, Wg2, bg2, Wc2, bc2,
                         Wh, bh, Wp, bp, out, ws);
    }
  }
}

// Round 9
// 3776.935 us; speedup vs baseline: 1.4664x; 1.4664x over previous
//
#include <hip/hip_runtime.h>
#include <cstdint>
#include <cstddef>

// ---------------------------------------------------------------------------
// VWFutureModel: 2-layer GRU scan (T=128, N=256, C=64, U=512) + dense head.
// R9 = R8 resubmission (pod died before running R8; design audit found no
// hang mechanism: no device-side spins, no barriers, bounded everything).
// Graph-of-kernels: 387 small launches; kernel boundaries provide cross-XCD
// visibility (CP-managed release/acquire), so ALL data-path accesses are
// plain cached loads/stores:
//  - weights: n = wg&31 -> all same-n WGs on XCD n%8 -> each weight slice
//    L2-resident on exactly one XCD (~1.3 MB/XCD)
//  - exchange (h planes, rh, gates, hid): normal stores/loads, L2-shared
//    within an XCD, full cached L3 bandwidth across XCDs
// Per step: S1=[P2+P2b], S2=[P3+P4b], S3=[P4 + P1(t+1)] (P1(t+1) depends
// only on P2(t)). Bit-identical arithmetic to R5/R7 (absmax 0.001953125).
// fp32 fallback kernel kept for small ws.
// ---------------------------------------------------------------------------

#define NWG 256
#define TPB 512

constexpr int N_ = 256, T_ = 128, C_ = 64, U_ = 512, H_ = 256;

typedef __attribute__((ext_vector_type(8))) short short8;
typedef __attribute__((ext_vector_type(4))) float f32x4;

// ---------------- byte offsets in workspace --------------------------------
constexpr size_t HPB      = 262144;                 // one h plane: 256*512*2B
constexpr size_t OFF_HP   = 16384;                  // 2 bufs x [h1hi,h1lo,h2hi,h2lo]
constexpr size_t OFF_RH1  = OFF_HP + 8 * HPB;
constexpr size_t OFF_RH2  = OFF_RH1 + 524288;
constexpr size_t OFF_G1U  = OFF_RH2 + 524288;       // fp32 [256][512]
constexpr size_t OFF_G2U  = OFF_G1U + 524288;
constexpr size_t OFF_HID  = OFF_G2U + 524288;       // hid hi,lo (2*131072)
constexpr size_t OFF_XHI  = OFF_HID + 262144;       // [256][8192] bf16
constexpr size_t OFF_XLO  = OFF_XHI + 4194304;
constexpr size_t OFF_WG1S = OFF_XLO + 4194304;      // 32 * 81920
constexpr size_t OFF_WC1S = OFF_WG1S + 32 * 81920;  // 32 * 40960
constexpr size_t OFF_WG2S = OFF_WC1S + 32 * 40960;  // 32 * 131072
constexpr size_t OFF_WC2S = OFF_WG2S + 32 * 131072; // 32 * 65536
constexpr size_t OFF_WHS  = OFF_WC2S + 32 * 65536;  // 16 * 32768
constexpr size_t OFF_WPS  = OFF_WHS + 16 * 32768;   // 4 * 16384
constexpr size_t WS_NEED  = OFF_WPS + 4 * 16384;    // ~22.6 MiB

// ---------------- scalar helpers -------------------------------------------
__device__ __forceinline__ float sigmoidf_(float z) {
  return 1.0f / (1.0f + __expf(-z));
}
__device__ __forceinline__ float tanhf_(float z) {
  return 1.0f - 2.0f / (1.0f + __expf(2.0f * z));
}
__device__ __forceinline__ unsigned short bf_hi(float f) {
  unsigned int x = __float_as_uint(f);
  unsigned int r = x + 0x7FFFu + ((x >> 16) & 1u);
  return (unsigned short)(r >> 16);
}
__device__ __forceinline__ float bf_f(unsigned v) {  // low 16 bits as bf16
  return __uint_as_float((v & 0xFFFFu) << 16);
}
__device__ __forceinline__ float bf_fh(unsigned v) {  // high 16 bits as bf16
  return __uint_as_float(v & 0xFFFF0000u);
}
__device__ __forceinline__ unsigned short bf_lo(float f, unsigned short hi) {
  return bf_hi(f - __uint_as_float(((unsigned)hi) << 16));
}

// ---------------- weight stream swizzle (prologue; zero-padded) ------------
__device__ void writeStream(const float* __restrict__ W, int ldW, int colbase,
                            char* sb, int nsplit, int slots, int tnn, int nch) {
  const int tid = threadIdx.x;
  const int lane = tid & 63;
  const int e = tid >> 6;  // 0..7
  const int nf = nsplit * slots * tnn;
  for (int f = 0; f < nf; ++f) {
    int tn = f % tnn;
    int ci = (f / tnn) % slots;
    int ks = f / (tnn * slots);
    int c = ks + ci * nsplit;
    int k = 32 * c + ((lane >> 4) << 3) + e;
    int col = colbase + 16 * tn + (lane & 15);
    float v = (c < nch) ? W[(size_t)k * ldW + col] : 0.f;
    unsigned short hi = bf_hi(v);
    unsigned short lo = bf_lo(v, hi);
    unsigned short* fb = (unsigned short*)(sb + (size_t)f * 2048);
    fb[lane * 8 + e] = hi;
    fb[512 + lane * 8 + e] = lo;
  }
}

// ---------------- MFMA core (plain cached loads) ---------------------------
template <int TM, int TN, int NSPLIT, int SLOTS, int KA>
__device__ __forceinline__ void mm_core(
    const unsigned short* __restrict__ A1h, const unsigned short* __restrict__ A1l,
    int lda1, int aoff,
    const unsigned short* __restrict__ A2h, const unsigned short* __restrict__ A2l,
    int lda2, const char* __restrict__ bstr, float* red, int row0loc) {
  const int tid = threadIdx.x;
  const int ww = tid >> 6, lane = tid & 63;
  const int tm = ww / NSPLIT;
  const int ks = ww % NSPLIT;
  const int arow = row0loc + 16 * tm + (lane & 15);
  const int kgrp = (lane >> 4) << 3;

  uint4 Ah[SLOTS], Al[SLOTS];
#pragma unroll
  for (int ci = 0; ci < SLOTS; ++ci) {
    const int c = ks + ci * NSPLIT;
    const int ak = 32 * c + kgrp;
    const unsigned short *ph, *pl;
    if (ak < KA) {
      ph = A1h + (size_t)arow * lda1 + aoff + ak;
      pl = A1l + (size_t)arow * lda1 + aoff + ak;
    } else {
      const int ak2 = ak - KA;
      ph = A2h + (size_t)arow * lda2 + ak2;
      pl = A2l + (size_t)arow * lda2 + ak2;
    }
    Ah[ci] = *(const uint4*)ph;
    Al[ci] = *(const uint4*)pl;
  }

  f32x4 acc0[TN], acc1[TN], acc2[TN];
#pragma unroll
  for (int tn = 0; tn < TN; ++tn) {
    acc0[tn] = (f32x4){0.f, 0.f, 0.f, 0.f};
    acc1[tn] = (f32x4){0.f, 0.f, 0.f, 0.f};
    acc2[tn] = (f32x4){0.f, 0.f, 0.f, 0.f};
  }
#pragma unroll
  for (int ci = 0; ci < SLOTS; ++ci) {
    union { uint4 u; short8 s; } ah, al;
    ah.u = Ah[ci]; al.u = Al[ci];
    const char* fb = bstr + ((size_t)(ks * SLOTS + ci) * TN) * 2048;
#pragma unroll
    for (int tn = 0; tn < TN; ++tn) {
      union { uint4 u; short8 s; } bh, bl;
      bh.u = *(const uint4*)((const unsigned short*)(fb + (size_t)tn * 2048) + lane * 8);
      bl.u = *(const uint4*)((const unsigned short*)(fb + (size_t)tn * 2048 + 1024) + lane * 8);
      acc0[tn] = __builtin_amdgcn_mfma_f32_16x16x32_bf16(ah.s, bh.s, acc0[tn], 0, 0, 0);
      acc1[tn] = __builtin_amdgcn_mfma_f32_16x16x32_bf16(ah.s, bl.s, acc1[tn], 0, 0, 0);
      acc2[tn] = __builtin_amdgcn_mfma_f32_16x16x32_bf16(al.s, bh.s, acc2[tn], 0, 0, 0);
    }
  }
#pragma unroll
  for (int tn = 0; tn < TN; ++tn) {
    f32x4 s = acc0[tn] + acc1[tn] + acc2[tn];
    int slot = (tm * TN + tn) * NSPLIT + ks;
    *(f32x4*)(&red[slot * 256 + lane * 4]) = s;
  }
}

// reduce partials + run epilogue per COLUMN-PAIR (col, col+1)
template <int TM, int TN, int NSPLIT, typename F>
__device__ __forceinline__ void epi2(const float* red, int row0loc, int col0, F f) {
  for (int idx = threadIdx.x; idx < TM * TN * 128; idx += TPB) {
    int tg = idx >> 7;
    int r  = (idx >> 3) & 15;
    int cp = idx & 7;
    int e0 = (((((r >> 2) << 4) | (cp << 1)) << 2) | (r & 3));
    float z0 = 0.f, z1 = 0.f;
#pragma unroll
    for (int s = 0; s < NSPLIT; ++s) {
      const float* rp = red + (tg * NSPLIT + s) * 256;
      z0 += rp[e0];
      z1 += rp[e0 + 4];
    }
    int tm = tg / TN, tn = tg % TN;
    f(row0loc + 16 * tm + r, col0 + 16 * tn + cp * 2, z0, z1);
  }
}

// ---------------- shared pointer helpers -----------------------------------
struct Ptrs {
  unsigned short *xhi, *xlo, *rh1hi, *rh1lo, *rh2hi, *rh2lo, *hidhi, *hidlo;
  float *g1u, *g2u;
};
__device__ __forceinline__ Ptrs mkptrs(char* wsb) {
  Ptrs p;
  p.xhi = (unsigned short*)(wsb + OFF_XHI);
  p.xlo = (unsigned short*)(wsb + OFF_XLO);
  p.rh1hi = (unsigned short*)(wsb + OFF_RH1);
  p.rh1lo = (unsigned short*)(wsb + OFF_RH1 + 262144);
  p.rh2hi = (unsigned short*)(wsb + OFF_RH2);
  p.rh2lo = (unsigned short*)(wsb + OFF_RH2 + 262144);
  p.hidhi = (unsigned short*)(wsb + OFF_HID);
  p.hidlo = (unsigned short*)(wsb + OFF_HID + 131072);
  p.g1u = (float*)(wsb + OFF_G1U);
  p.g2u = (float*)(wsb + OFF_G2U);
  return p;
}
__device__ __forceinline__ unsigned short* hplane(char* wsb, int parity) {
  return (unsigned short*)(wsb + OFF_HP + (size_t)parity * 4 * HPB);
}

// P1 body (shared by k_p1 and k_s3): step index ts, parity ps = ts&1.
__device__ __forceinline__ void p1_body(char* wsb, const float* __restrict__ bg1,
                                        int ts, int m, int n, float* red) {
  const int row0 = m * 32;
  const int ps = ts & 1;
  Ptrs pp = mkptrs(wsb);
  unsigned short* h1hi_p = hplane(wsb, ps);
  unsigned short* h1lo_p = h1hi_p + 131072;
  const char* wg1s = (const char*)(wsb + OFF_WG1S + (size_t)n * 81920);
  mm_core<2, 2, 4, 5, 64>(pp.xhi, pp.xlo, 8192, ts * 64, h1hi_p, h1lo_p, 512,
                          wg1s, red, row0);
  __syncthreads();
  epi2<2, 2, 4>(red, row0, n * 32, [&](int row, int col, float z0, float z1) {
    z0 += bg1[col]; z1 += bg1[col + 1];
    float s0 = sigmoidf_(z0), s1 = sigmoidf_(z1);
    if (col < 512) {
      size_t ix = (size_t)row * 512 + col;
      unsigned hw = *(const unsigned*)(h1hi_p + ix);
      unsigned lw = *(const unsigned*)(h1lo_p + ix);
      float h0 = bf_f(hw) + bf_f(lw);
      float h1v = bf_fh(hw) + bf_fh(lw);
      float r0 = s0 * h0, r1 = s1 * h1v;
      unsigned short a0 = bf_hi(r0), a1 = bf_hi(r1);
      *(unsigned*)(pp.rh1hi + ix) = (unsigned)a0 | ((unsigned)a1 << 16);
      *(unsigned*)(pp.rh1lo + ix) = (unsigned)bf_lo(r0, a0) | ((unsigned)bf_lo(r1, a1) << 16);
    } else {
      float2 g = {s0, s1};
      *(float2*)(pp.g1u + (size_t)row * 512 + (col - 512)) = g;
    }
  });
}

// ---------------- kernels --------------------------------------------------
extern "C" __global__ __launch_bounds__(TPB, 2)
void k_prolog(const float* __restrict__ frames,
              const float* __restrict__ Wg1, const float* __restrict__ Wc1,
              const float* __restrict__ Wg2, const float* __restrict__ Wc2,
              const float* __restrict__ Wh, const float* __restrict__ Wp,
              char* __restrict__ wsb) {
  const int tid = threadIdx.x;
  const int wg = blockIdx.x;
  unsigned short* xhi = (unsigned short*)(wsb + OFF_XHI);
  unsigned short* xlo = (unsigned short*)(wsb + OFF_XLO);
  const size_t base = (size_t)wg * 8192;
  for (int i = tid; i < 8192; i += TPB) {
    float v = frames[base + i];
    unsigned short h = bf_hi(v);
    xhi[base + i] = h;
    xlo[base + i] = bf_lo(v, h);
  }
  if (wg < 32) {
    writeStream(Wg1, 1024, wg * 32, wsb + OFF_WG1S + (size_t)wg * 81920, 4, 5, 2, 18);
    writeStream(Wc1, 512, wg * 16, wsb + OFF_WC1S + (size_t)wg * 40960, 4, 5, 1, 18);
    writeStream(Wg2, 1024, wg * 32, wsb + OFF_WG2S + (size_t)wg * 131072, 4, 8, 2, 32);
    writeStream(Wc2, 512, wg * 16, wsb + OFF_WC2S + (size_t)wg * 65536, 4, 8, 1, 32);
  }
  if (wg < 16) writeStream(Wh, 256, wg * 16, wsb + OFF_WHS + (size_t)wg * 32768, 8, 2, 1, 16);
  if (wg < 4)  writeStream(Wp, 64, wg * 16, wsb + OFF_WPS + (size_t)wg * 16384, 8, 1, 1, 8);
}

extern "C" __global__ __launch_bounds__(TPB, 2)
void k_p1(char* __restrict__ wsb, const float* __restrict__ bg1, int t) {
  __shared__ float red[4096];
  const int wg = blockIdx.x;
  p1_body(wsb, bg1, t, wg >> 5, wg & 31, red);
}

// S1 = P2 (t<T_) + P2b (t>0)
extern "C" __global__ __launch_bounds__(TPB, 2)
void k_s1(char* __restrict__ wsb, const float* __restrict__ bc1,
          const float* __restrict__ bh, int t) {
  __shared__ float red[4096];
  const int wg = blockIdx.x;
  const int m = wg >> 5, n = wg & 31;
  const int row0 = m * 32;
  const int p = t & 1, q = p ^ 1;
  Ptrs pp = mkptrs(wsb);
  unsigned short* h1hi_p = hplane(wsb, p);
  unsigned short* h1lo_p = h1hi_p + 131072;
  unsigned short* h2hi_p = h1hi_p + 262144;
  unsigned short* h2lo_p = h1hi_p + 393216;
  unsigned short* h1hi_q = hplane(wsb, q);
  unsigned short* h1lo_q = h1hi_q + 131072;
  const char* wc1s = (const char*)(wsb + OFF_WC1S + (size_t)n * 40960);
  const int b2 = n & 15, a2 = n >> 4;
  const char* whs = (const char*)(wsb + OFF_WHS + (size_t)b2 * 32768);

  if (t < T_)
    mm_core<2, 1, 4, 5, 64>(pp.xhi, pp.xlo, 8192, t * 64, pp.rh1hi, pp.rh1lo, 512,
                            wc1s, red, row0);
  if (t > 0)
    mm_core<1, 1, 8, 2, 512>(h2hi_p, h2lo_p, 512, 0, nullptr, nullptr, 0,
                             whs, red + 2048, row0 + 16 * a2);
  __syncthreads();
  if (t < T_) {
    epi2<2, 1, 4>(red, row0, n * 16, [&](int row, int col, float z0, float z1) {
      z0 += bc1[col]; z1 += bc1[col + 1];
      float c0 = tanhf_(z0), c1 = tanhf_(z1);
      size_t ix = (size_t)row * 512 + col;
      float2 ug = *(const float2*)(pp.g1u + ix);
      unsigned hw = *(const unsigned*)(h1hi_p + ix);
      unsigned lw = *(const unsigned*)(h1lo_p + ix);
      float h0 = bf_f(hw) + bf_f(lw);
      float h1v = bf_fh(hw) + bf_fh(lw);
      float n0 = ug.x * h0 + (1.f - ug.x) * c0;
      float n1 = ug.y * h1v + (1.f - ug.y) * c1;
      unsigned short a0 = bf_hi(n0), a1 = bf_hi(n1);
      *(unsigned*)(h1hi_q + ix) = (unsigned)a0 | ((unsigned)a1 << 16);
      *(unsigned*)(h1lo_q + ix) = (unsigned)bf_lo(n0, a0) | ((unsigned)bf_lo(n1, a1) << 16);
    });
  }
  if (t > 0) {
    epi2<1, 1, 8>(red + 2048, row0 + 16 * a2, 16 * b2,
                  [&](int row, int col, float z0, float z1) {
      z0 += bh[col]; z1 += bh[col + 1];
      float e0v = z0 > 0.f ? z0 : __expf(z0) - 1.f;
      float e1v = z1 > 0.f ? z1 : __expf(z1) - 1.f;
      size_t ix = (size_t)row * 256 + col;
      unsigned short a0 = bf_hi(e0v), a1 = bf_hi(e1v);
      *(unsigned*)(pp.hidhi + ix) = (unsigned)a0 | ((unsigned)a1 << 16);
      *(unsigned*)(pp.hidlo + ix) = (unsigned)bf_lo(e0v, a0) | ((unsigned)bf_lo(e1v, a1) << 16);
    });
  }
}

// S2 = P3 (t<T_) + P4b (t>0, n<8)
extern "C" __global__ __launch_bounds__(TPB, 2)
void k_s2(char* __restrict__ wsb, const float* __restrict__ bg2,
          const float* __restrict__ bp, float* __restrict__ out, int t) {
  __shared__ float red[6144];
  const int wg = blockIdx.x;
  const int m = wg >> 5, n = wg & 31;
  const int row0 = m * 32;
  const int p = t & 1, q = p ^ 1;
  Ptrs pp = mkptrs(wsb);
  unsigned short* h1hi_p = hplane(wsb, p);
  unsigned short* h2hi_p = h1hi_p + 262144;
  unsigned short* h2lo_p = h1hi_p + 393216;
  unsigned short* h1hi_q = hplane(wsb, q);
  unsigned short* h1lo_q = h1hi_q + 131072;
  const char* wg2s = (const char*)(wsb + OFF_WG2S + (size_t)n * 131072);
  const int b4 = n & 3, a4 = (n >> 2) & 1;
  const char* wps = (const char*)(wsb + OFF_WPS + (size_t)b4 * 16384);

  if (t < T_)
    mm_core<2, 2, 4, 8, 512>(h1hi_q, h1lo_q, 512, 0, h2hi_p, h2lo_p, 512,
                             wg2s, red, row0);
  if (t > 0 && n < 8)
    mm_core<1, 1, 8, 1, 256>(pp.hidhi, pp.hidlo, 256, 0, nullptr, nullptr, 0,
                             wps, red + 4096, row0 + 16 * a4);
  __syncthreads();
  if (t < T_) {
    epi2<2, 2, 4>(red, row0, n * 32, [&](int row, int col, float z0, float z1) {
      z0 += bg2[col]; z1 += bg2[col + 1];
      float s0 = sigmoidf_(z0), s1 = sigmoidf_(z1);
      if (col < 512) {
        size_t ix = (size_t)row * 512 + col;
        unsigned hw = *(const unsigned*)(h2hi_p + ix);
        unsigned lw = *(const unsigned*)(h2lo_p + ix);
        float h0 = bf_f(hw) + bf_f(lw);
        float h1v = bf_fh(hw) + bf_fh(lw);
        float r0 = s0 * h0, r1 = s1 * h1v;
        unsigned short a0 = bf_hi(r0), a1 = bf_hi(r1);
        *(unsigned*)(pp.rh2hi + ix) = (unsigned)a0 | ((unsigned)a1 << 16);
        *(unsigned*)(pp.rh2lo + ix) = (unsigned)bf_lo(r0, a0) | ((unsigned)bf_lo(r1, a1) << 16);
      } else {
        float2 g = {s0, s1};
        *(float2*)(pp.g2u + (size_t)row * 512 + (col - 512)) = g;
      }
    });
  }
  if (t > 0 && n < 8) {
    epi2<1, 1, 8>(red + 4096, row0 + 16 * a4, 16 * b4,
                  [&](int row, int col, float z0, float z1) {
      float2 v = {z0 + bp[col], z1 + bp[col + 1]};
      *(float2*)(out + (size_t)row * 8192 + (size_t)(t - 1) * 64 + col) = v;
    });
  }
}

// S3 = P4 (t<T_) + P1(t+1) (t+1<T_)
extern "C" __global__ __launch_bounds__(TPB, 2)
void k_s3(char* __restrict__ wsb, const float* __restrict__ bc2,
          const float* __restrict__ bg1, int t) {
  __shared__ float red[6144];
  const int wg = blockIdx.x;
  const int m = wg >> 5, n = wg & 31;
  const int row0 = m * 32;
  const int p = t & 1, q = p ^ 1;
  Ptrs pp = mkptrs(wsb);
  unsigned short* h1hi_p = hplane(wsb, p);
  unsigned short* h2hi_p = h1hi_p + 262144;
  unsigned short* h2lo_p = h1hi_p + 393216;
  unsigned short* h1hi_q = hplane(wsb, q);
  unsigned short* h1lo_q = h1hi_q + 131072;
  unsigned short* h2hi_q = h1hi_q + 262144;
  unsigned short* h2lo_q = h1hi_q + 393216;
  const char* wc2s = (const char*)(wsb + OFF_WC2S + (size_t)n * 65536);

  mm_core<2, 1, 4, 8, 512>(h1hi_q, h1lo_q, 512, 0, pp.rh2hi, pp.rh2lo, 512,
                           wc2s, red, row0);
  __syncthreads();
  epi2<2, 1, 4>(red, row0, n * 16, [&](int row, int col, float z0, float z1) {
    z0 += bc2[col]; z1 += bc2[col + 1];
    float c0 = tanhf_(z0), c1 = tanhf_(z1);
    size_t ix = (size_t)row * 512 + col;
    float2 ug = *(const float2*)(pp.g2u + ix);
    unsigned hw = *(const unsigned*)(h2hi_p + ix);
    unsigned lw = *(const unsigned*)(h2lo_p + ix);
    float h0 = bf_f(hw) + bf_f(lw);
    float h1v = bf_fh(hw) + bf_fh(lw);
    float n0 = ug.x * h0 + (1.f - ug.x) * c0;
    float n1 = ug.y * h1v + (1.f - ug.y) * c1;
    unsigned short a0 = bf_hi(n0), a1 = bf_hi(n1);
    *(unsigned*)(h2hi_q + ix) = (unsigned)a0 | ((unsigned)a1 << 16);
    *(unsigned*)(h2lo_q + ix) = (unsigned)bf_lo(n0, a0) | ((unsigned)bf_lo(n1, a1) << 16);
  });
  // P1 for step t+1 (reads h1 plane q written by k_s1(t); disjoint outputs).
  if (t + 1 < T_) {
    __syncthreads();
    p1_body(wsb, bg1, t + 1, m, n, red + 2048);
  }
}

// ======================= R2 fallback (proven fp32 path) ====================
constexpr size_t F_SZ_H   = (size_t)N_ * U_;
constexpr size_t F_OFF_H1 = 0;
constexpr size_t F_OFF_H2 = F_OFF_H1 + 2 * F_SZ_H;
constexpr size_t F_OFF_BAR = F_OFF_H2 + 2 * F_SZ_H;
constexpr size_t F_OFF_G1 = F_OFF_BAR + 64;
constexpr size_t F_OFF_G2 = F_OFF_G1 + (size_t)N_ * 1024;
constexpr size_t F_OFF_HID = F_OFF_G2 + (size_t)N_ * 1024;
constexpr int LDP = 257;

__device__ __forceinline__ void gbarF(unsigned* b, unsigned np) {
  __syncthreads();
  if (threadIdx.x == 0) {
    __threadfence();
    unsigned e = __hip_atomic_load(b + 16, __ATOMIC_RELAXED, __HIP_MEMORY_SCOPE_AGENT);
    unsigned a = __hip_atomic_fetch_add(b, 1u, __ATOMIC_ACQ_REL, __HIP_MEMORY_SCOPE_AGENT);
    if (a == np - 1) {
      __hip_atomic_store(b, 0u, __ATOMIC_RELAXED, __HIP_MEMORY_SCOPE_AGENT);
      __hip_atomic_store(b + 16, e + 1u, __ATOMIC_RELEASE, __HIP_MEMORY_SCOPE_AGENT);
    } else {
      unsigned spins = 0;
      while (__hip_atomic_load(b + 16, __ATOMIC_RELAXED, __HIP_MEMORY_SCOPE_AGENT) == e) {
        __builtin_amdgcn_s_sleep(1);
        if (++spins > (1u << 20)) break;
      }
    }
    __threadfence();
  }
  __syncthreads();
}

template <int CK, bool GATED>
__device__ __forceinline__ void stage(float (*lds)[LDP],
                                      const float* __restrict__ src, int sStride, int sOff,
                                      const float* __restrict__ gate, int gStride, int gOff,
                                      int row0) {
  constexpr int PER = CK / 16;
  const int r = threadIdx.x >> 4;
  const int c0 = (threadIdx.x & 15) * PER;
  const float* s = src + (size_t)(row0 + r) * sStride + sOff + c0;
  float4 a0, a1, a2, a3;
  a0 = *(const float4*)(s);
  if constexpr (PER >= 8) a1 = *(const float4*)(s + 4);
  if constexpr (PER >= 16) { a2 = *(const float4*)(s + 8); a3 = *(const float4*)(s + 12); }
  if constexpr (GATED) {
    const float* g = gate + (size_t)(row0 + r) * gStride + gOff + c0;
    float4 g0 = *(const float4*)(g);
    a0.x *= g0.x; a0.y *= g0.y; a0.z *= g0.z; a0.w *= g0.w;
    if constexpr (PER >= 8) {
      float4 g1v = *(const float4*)(g + 4);
      a1.x *= g1v.x; a1.y *= g1v.y; a1.z *= g1v.z; a1.w *= g1v.w;
    }
    if constexpr (PER >= 16) {
      float4 g2v = *(const float4*)(g + 8);
      float4 g3v = *(const float4*)(g + 12);
      a2.x *= g2v.x; a2.y *= g2v.y; a2.z *= g2v.z; a2.w *= g2v.w;
      a3.x *= g3v.x; a3.y *= g3v.y; a3.z *= g3v.z; a3.w *= g3v.w;
    }
  }
  float* d = &lds[r][c0];
  d[0] = a0.x; d[1] = a0.y; d[2] = a0.z; d[3] = a0.w;
  if constexpr (PER >= 8) { d[4] = a1.x; d[5] = a1.y; d[6] = a1.z; d[7] = a1.w; }
  if constexpr (PER >= 16) {
    d[8] = a2.x; d[9] = a2.y; d[10] = a2.z; d[11] = a2.w;
    d[12] = a3.x; d[13] = a3.y; d[14] = a3.z; d[15] = a3.w;
  }
}
template <int CK>
__device__ __forceinline__ void fma2(float2& acc, const float (*lds)[LDP], int row,
                                     const float* __restrict__ B, int ldB) {
#pragma unroll 8
  for (int k = 0; k < CK; ++k) {
    const float a = lds[row][k];
    const float2 b = *(const float2*)(B + (size_t)k * ldB);
    acc.x = fmaf(a, b.x, acc.x);
    acc.y = fmaf(a, b.y, acc.y);
  }
}
template <int CK>
__device__ __forceinline__ void fma1(float& acc, const float (*lds)[LDP], int row,
                                     const float* __restrict__ B, int ldB) {
#pragma unroll 8
  for (int k = 0; k < CK; ++k) acc = fmaf(lds[row][k], B[(size_t)k * ldB], acc);
}

extern "C" __global__ __launch_bounds__(TPB, 2)
void gru_persistent(const float* __restrict__ frames,
                    const float* __restrict__ Wg1, const float* __restrict__ bg1,
                    const float* __restrict__ Wc1, const float* __restrict__ bc1,
                    const float* __restrict__ Wg2, const float* __restrict__ bg2,
                    const float* __restrict__ Wc2, const float* __restrict__ bc2,
                    const float* __restrict__ Wh,  const float* __restrict__ bh,
                    const float* __restrict__ Wp,  const float* __restrict__ bp,
                    float* __restrict__ out, float* __restrict__ ws) {
  __shared__ float lds[32][LDP];
  float* h1b = ws + F_OFF_H1;
  float* h2b = ws + F_OFF_H2;
  unsigned* bar = (unsigned*)(ws + F_OFF_BAR);
  float* g1 = ws + F_OFF_G1;
  float* g2 = ws + F_OFF_G2;
  float* hid = ws + F_OFF_HID;
  const int tid = threadIdx.x;
  const int wg = blockIdx.x;
  const int xcd = wg & 7, grp = wg >> 3;
  const int m_blk = grp >> 2, n_blk = (xcd << 2) | (grp & 3);
  const int row0 = m_blk * 32;
  const int rowA = tid & 31, cq = tid >> 5;
  const int nrow = row0 + rowA;
  for (int t = 0; t <= T_; ++t) {
    const int p = t & 1;
    const float* h1o = h1b + (size_t)p * F_SZ_H;
    float* h1n = h1b + (size_t)(p ^ 1) * F_SZ_H;
    const float* h2o = h2b + (size_t)p * F_SZ_H;
    float* h2n = h2b + (size_t)(p ^ 1) * F_SZ_H;
    if (t < T_) {
      float2 acc = {0.f, 0.f};
      const int col = n_blk * 32 + cq * 2;
      stage<64, false>(lds, frames, T_ * C_, t * C_, nullptr, 0, 0, row0);
      __syncthreads();
      fma2<64>(acc, lds, rowA, Wg1 + col, 1024);
      __syncthreads();
#pragma unroll 1
      for (int ch = 0; ch < 2; ++ch) {
        stage<256, false>(lds, h1o, U_, ch * 256, nullptr, 0, 0, row0);
        __syncthreads();
        fma2<256>(acc, lds, rowA, Wg1 + (size_t)(64 + ch * 256) * 1024 + col, 1024);
        __syncthreads();
      }
      const float2 bb = *(const float2*)(bg1 + col);
      float* gp = g1 + (size_t)nrow * 1024 + col;
      gp[0] = sigmoidf_(acc.x + bb.x);
      gp[1] = sigmoidf_(acc.y + bb.y);
    }
    gbarF(bar, NWG);
    if (t < T_) {
      float acc = 0.f;
      const int col = n_blk * 16 + cq;
      stage<64, false>(lds, frames, T_ * C_, t * C_, nullptr, 0, 0, row0);
      __syncthreads();
      fma1<64>(acc, lds, rowA, Wc1 + col, U_);
      __syncthreads();
#pragma unroll 1
      for (int ch = 0; ch < 2; ++ch) {
        stage<256, true>(lds, h1o, U_, ch * 256, g1, 1024, ch * 256, row0);
        __syncthreads();
        fma1<256>(acc, lds, rowA, Wc1 + (size_t)(64 + ch * 256) * U_ + col, U_);
        __syncthreads();
      }
      const float cv = tanhf_(acc + bc1[col]);
      const float u = g1[(size_t)nrow * 1024 + 512 + col];
      const float ho = h1o[(size_t)nrow * U_ + col];
      h1n[(size_t)nrow * U_ + col] = u * ho + (1.f - u) * cv;
    }
    if (t > 0) {
      float acc = 0.f;
      const int col = n_blk * 8 + (cq & 7);
      const bool act = tid < 256;
#pragma unroll 1
      for (int ch = 0; ch < 2; ++ch) {
        stage<256, false>(lds, h2o, U_, ch * 256, nullptr, 0, 0, row0);
        __syncthreads();
        if (act) fma1<256>(acc, lds, rowA, Wh + (size_t)(ch * 256) * H_ + col, H_);
        __syncthreads();
      }
      if (act) {
        const float z = acc + bh[col];
        hid[(size_t)nrow * H_ + col] = z > 0.f ? z : __expf(z) - 1.f;
      }
    }
    gbarF(bar, NWG);
    if (t < T_) {
      float2 acc = {0.f, 0.f};
      const int col = n_blk * 32 + cq * 2;
#pragma unroll 1
      for (int ch = 0; ch < 4; ++ch) {
        const float* src = (ch < 2) ? h1n : h2o;
        stage<256, false>(lds, src, U_, (ch & 1) * 256, nullptr, 0, 0, row0);
        __syncthreads();
        fma2<256>(acc, lds, rowA, Wg2 + (size_t)(ch * 256) * 1024 + col, 1024);
        __syncthreads();
      }
      const float2 bb = *(const float2*)(bg2 + col);
      float* gp = g2 + (size_t)nrow * 1024 + col;
      gp[0] = sigmoidf_(acc.x + bb.x);
      gp[1] = sigmoidf_(acc.y + bb.y);
    }
    gbarF(bar, NWG);
    if (t < T_) {
      float acc = 0.f;
      const int col = n_blk * 16 + cq;
#pragma unroll 1
      for (int ch = 0; ch < 4; ++ch) {
        if (ch < 2) stage<256, false>(lds, h1n, U_, (ch & 1) * 256, nullptr, 0, 0, row0);
        else stage<256, true>(lds, h2o, U_, (ch & 1) * 256, g2, 1024, (ch & 1) * 256, row0);
        __syncthreads();
        fma1<256>(acc, lds, rowA, Wc2 + (size_t)(ch * 256) * U_ + col, U_);
        __syncthreads();
      }
      const float cv = tanhf_(acc + bc2[col]);
      const float u = g2[(size_t)nrow * 1024 + 512 + col];
      const float ho = h2o[(size_t)nrow * U_ + col];
      h2n[(size_t)nrow * U_ + col] = u * ho + (1.f - u) * cv;
    }
    if (t > 0) {
      if (tid < 64) {
        float acc = 0.f;
        const int col = n_blk * 2 + cq;
        const float* hrow = hid + (size_t)nrow * H_;
#pragma unroll 8
        for (int k = 0; k < H_; ++k) acc = fmaf(hrow[k], Wp[(size_t)k * C_ + col], acc);
        out[(size_t)nrow * (T_ * C_) + (size_t)(t - 1) * C_ + col] = acc + bp[col];
      }
    }
  }
}

// ---------------- launch ---------------------------------------------------
extern "C" void kernel_launch(void* const* d_in, const int* in_sizes, int n_in,
                              void* d_out, int out_size, void* d_ws, size_t ws_size,
                              hipStream_t stream) {
  const float* frames = (const float*)d_in[0];
  const float* Wg1 = (const float*)d_in[1];
  const float* bg1 = (const float*)d_in[2];
  const float* Wc1 = (const float*)d_in[3];
  const float* bc1 = (const float*)d_in[4];
  const float* Wg2 = (const float*)d_in[5];
  const float* bg2 = (const float*)d_in[6];
  const float* Wc2 = (const float*)d_in[7];
  const float* bc2 = (const float*)d_in[8];
  const float* Wh = (const float*)d_in[9];
  const float* bh = (const float*)d_in[10];
  const float* Wp = (const float*)d_in[11];
  const float* bp = (const float*)d_in[12];
  float* out = (float*)d_out;

  if (ws_size >= WS_NEED) {
    char* wsb = (char*)d_ws;
    hipMemsetAsync(d_ws, 0, 16384 + 4 * HPB, stream);  // zero h-plane buffer 0
    hipLaunchKernelGGL(k_prolog, dim3(NWG), dim3(TPB), 0, stream,
                       frames, Wg1, Wc1, Wg2, Wc2, Wh, Wp, wsb);
    hipLaunchKernelGGL(k_p1, dim3(NWG), dim3(TPB), 0, stream, wsb, bg1, 0);
    for (int t = 0; t <= T_; ++t) {
      hipLaunchKernelGGL(k_s1, dim3(NWG), dim3(TPB), 0, stream, wsb, bc1, bh, t);
      hipLaunchKernelGGL(k_s2, dim3(NWG), dim3(TPB), 0, stream, wsb, bg2, bp, out, t);
      if (t < T_)
        hipLaunchKernelGGL(k_s3, dim3(NWG), dim3(TPB), 0, stream, wsb, bc2, bg1, t);
    }
  } else {
    float* ws = (float*)d_ws;
    hipMemsetAsync(d_ws, 0, F_OFF_G1 * sizeof(float), stream);
    void* args[] = {(void*)&frames, (void*)&Wg1, (void*)&bg1, (void*)&Wc1, (void*)&bc1,
                    (void*)&Wg2, (void*)&bg2, (void*)&Wc2, (void*)&bc2,
                    (void*)&Wh, (void*)&bh, (void*)&Wp, (void*)&bp,
                    (void*)&out, (void*)&ws};
    hipError_t err = hipLaunchCooperativeKernel((const void*)gru_persistent,
                                                dim3(NWG), dim3(TPB), args, 0, stream);
    if (err != hipSuccess) {
      (void)hipGetLastError();
      hipLaunchKernelGGL(gru_persistent, dim3(NWG), dim3(TPB), 0, stream,
                         frames, Wg1, bg1, Wc1, bc1, Wg2, bg2, Wc2, bc2,
                         Wh, bh, Wp, bp, out, ws);
    }
  }
}